// Round 4
// baseline (667.871 us; speedup 1.0000x reference)
//
#include <hip/hip_runtime.h>
#include <cstdint>

typedef __bf16 bf16;
typedef __bf16 bf16x8 __attribute__((ext_vector_type(8)));
typedef __bf16 bf16x4 __attribute__((ext_vector_type(4)));
typedef float  f32x4  __attribute__((ext_vector_type(4)));

#define BQ     2
#define LQ     2048
#define DMODEL 2048
#define INTER  4096
#define NH     64
#define HD     64
#define NS     128
#define CS     256
#define NC     8
#define CONVD  4352
#define PROJD  8512
#define PROJP  8576   /* padded proj stride (128-multiple) */
#define PROJW  8704   /* W_in rows padded to 256-multiple for 256-wide GEMM tiles */
#define MTOT   4096   /* B*L */
#define EPSF   1e-5f
#define LOG2E  1.44269504088896f

// ---------------------------------------------------------------- utilities
__device__ __forceinline__ void async_ld16(const bf16* g, bf16* l) {
  __builtin_amdgcn_global_load_lds(
      (__attribute__((address_space(1))) void*)(uintptr_t)g,
      (__attribute__((address_space(3))) void*)l, 16, 0, 0);
}

__device__ __forceinline__ float siluf(float x) { return x / (1.f + expf(-x)); }

#define SB()    __builtin_amdgcn_sched_barrier(0)
#define HWBAR() __builtin_amdgcn_s_barrier()
#define LGKM0() asm volatile("s_waitcnt lgkmcnt(0)" ::: "memory")

// ---------------------------------------------------------------- casts
__global__ void cast4_k(const float* __restrict__ in, bf16* __restrict__ out, long n4) {
  long i = (long)blockIdx.x * 256 + threadIdx.x;
  if (i >= n4) return;
  float4 v = ((const float4*)in)[i];
  bf16x4 o; o[0] = (bf16)v.x; o[1] = (bf16)v.y; o[2] = (bf16)v.z; o[3] = (bf16)v.w;
  ((bf16x4*)out)[i] = o;
}

__global__ void cast_pad_win_k(const float* __restrict__ W, bf16* __restrict__ out) {
  long i = (long)blockIdx.x * 256 + threadIdx.x;       // over PROJW * (DMODEL/4)
  long tot = (long)PROJW * (DMODEL / 4);
  if (i >= tot) return;
  long row = i / (DMODEL / 4);
  long k4  = i % (DMODEL / 4);
  bf16x4 o;
  if (row < PROJD) {
    float4 v = ((const float4*)W)[row * (DMODEL / 4) + k4];
    o[0] = (bf16)v.x; o[1] = (bf16)v.y; o[2] = (bf16)v.z; o[3] = (bf16)v.w;
  } else {
    o[0] = o[1] = o[2] = o[3] = (bf16)0.f;
  }
  ((bf16x4*)out)[i] = o;
}

// ---------------------------------------------------------------- 256x256 8-phase GEMM  C = A(MxK) * W(NxK)^T
// 8 waves (2M x 4N), BK=64. LDS = 2 buffers x 64 KiB; per buffer:
//   part 0 = A[0:128), part 1 = A[128:256), part 2 = B[0:128), part 3 = B[128:256)
// Staging: global_load_lds x16B, linear LDS dest, XOR-8 pre-swizzled global source.
// Read swizzle: 16B-group g at row r lives at physical group g^(r&7) (conflict-free ds_read_b128).
//
// Schedule per K-tile T (4 phases). Reads: ph1 = b0-3(8)+a0-3(8), ph2 = a4-7(8), ph3/4 = none.
// MFMA quadrants: ph1 rows0-3 x nf0-1, ph2 rows4-7 x nf0-1, ph3 rows0-3 x nf2-3,
// ph4 rows4-7 x nf2-3 (b2-3 register-cached from ph1).
// Stages (slot-liveness staggered, leads 4-7 phases so vmcnt(6) never stalls on latency):
//   ph1: A1(T+1)  -> other buffer; that slot last read ph2 of T-1 (free).
//   ph2: B0(T+2)  -> CURRENT buffer; B slots last read ph1 (drained ph1 lgkm0 + barrier).
//   ph3: B1(T+2)  -> current buffer, same argument.
//   ph4: A0(T+2)  -> current buffer; A slots last read ph2 (drained ph2 lgkm0 + barrier).
// vmcnt (loads; 2 per half-tile per wave): queue at end-of-T =
//   [B0,B1,A0](T+1) 6 + A1(T+1) 2 + [B0,B1](T+2) 4 + A0(T+2) 2 = 14; vmcnt(6) retires
//   exactly tile T+1's four halves, leaving 3 halves of T+2 in flight (steady state).
//   vmcnt(0) when T+2 >= NT (drain tail).
// Prologue: tile0 all 4 halves + tile1.{B0,B1,A0}; vmcnt(6) retires tile0; A1(1) staged at
// T=0 ph1. Cross-wave DMA-vs-read safety: every stage into a slot is issued at least one
// barrier after every wave's lgkm0-drained last read of that slot.

template<int R0>
__device__ __forceinline__ void ldB4(bf16x8 (&dst)[4][2], const char* base,
                                     int r16, int quad, int xr) {
  #pragma unroll
  for (int f = 0; f < 4; ++f)
    #pragma unroll
    for (int kk = 0; kk < 2; ++kk)
      dst[f][kk] = *(const bf16x8*)(base + (((R0 + f) * 16 + r16) << 7)
                                         + ((((kk << 2) + quad) ^ xr) << 4));
}

template<int R0>
__device__ __forceinline__ void ldA4(bf16x8 (&dst)[8][2], const char* base,
                                     int r16, int quad, int xr) {
  #pragma unroll
  for (int f = 0; f < 4; ++f)
    #pragma unroll
    for (int kk = 0; kk < 2; ++kk)
      dst[R0 + f][kk] = *(const bf16x8*)(base + (((R0 + f) * 16 + r16) << 7)
                                              + ((((kk << 2) + quad) ^ xr) << 4));
}

template<int MH, int NHALF>
__device__ __forceinline__ void qmfma(f32x4 (&acc)[8][4], const bf16x8 (&a)[8][2],
                                      const bf16x8 (&b)[4][2]) {
  // mm varies fastest: consecutive MFMAs never share an accumulator
  #pragma unroll
  for (int kk = 0; kk < 2; ++kk)
    #pragma unroll
    for (int nf = 0; nf < 2; ++nf)
      #pragma unroll
      for (int mm = 0; mm < 4; ++mm)
        acc[MH * 4 + mm][NHALF * 2 + nf] = __builtin_amdgcn_mfma_f32_16x16x32_bf16(
            a[MH * 4 + mm][kk], b[NHALF * 2 + nf][kk], acc[MH * 4 + mm][NHALF * 2 + nf], 0, 0, 0);
}

__global__ __launch_bounds__(512, 2) void gemm8(
    const bf16* __restrict__ A, const bf16* __restrict__ W,
    bf16* __restrict__ Cb, float* __restrict__ Cf,
    int M, int Nn, int Ntiles, int K, int KS, int outf32)
{
  __shared__ int4 lds4[8192];            // 128 KiB
  char* lds = (char*)lds4;
  const int tid  = threadIdx.x;
  const int w    = tid >> 6;
  const int l    = tid & 63;
  const int wm   = w >> 2;               // 0..1
  const int wn   = w & 3;                // 0..3
  const int quad = l >> 4;
  const int r16  = l & 15;
  const int xr   = r16 & 7;

  const int Mtiles  = M >> 8;
  const int tilesMN = Mtiles * Ntiles;
  const int nwg = tilesMN * KS;
  int bid = blockIdx.x;
  int sid = ((nwg & 7) == 0) ? ((bid & 7) * (nwg >> 3) + (bid >> 3)) : bid;
  const int ks  = sid / tilesMN;
  const int rem = sid - ks * tilesMN;
  const int by = rem % Mtiles;
  const int bx = rem / Mtiles;
  const long tm = (long)by << 8;
  const long tn = (long)bx << 8;
  const int  NT = K / (64 * KS);
  const long kbase = (long)ks * (K / KS);

  // staging lane coords (round = 64 rows; lane covers 16B at swizzled k-group)
  const int srow = w * 8 + (l >> 3);
  const int scg  = (l & 7) ^ ((l >> 3) & 7);
  const bf16* Ab = A + (tm + srow) * K + kbase + scg * 8;
  const bf16* Wb = W + (tn + srow) * K + kbase + scg * 8;

  auto stage = [&](int tile, int part) {
    if (tile < NT) {
      const bf16* s = (part < 2 ? Ab : Wb) + (long)((part & 1) * 128) * K + (long)tile * 64;
      char* d = lds + ((tile & 1) << 16) + (part << 14) + (w << 10);
      async_ld16(s, (bf16*)d);
      async_ld16(s + (long)K * 64, (bf16*)(d + 8192));
    }
  };

  // ---- prologue: tile0 fully + tile1.{B0,B1,A0}; A1(1) staged during tile 0 ph1.
  stage(0, 0); stage(0, 1); stage(0, 2); stage(0, 3);
  stage(1, 2); stage(1, 3); stage(1, 0);
  asm volatile("s_waitcnt vmcnt(6)" ::: "memory");   // tile0 landed, 3 halves of tile1 in flight
  SB();
  HWBAR();

  f32x4 acc[8][4] = {};

  for (int T = 0; T < NT; ++T) {
    const int bsel = (T & 1) << 16;
    const char* as = lds + bsel + (wm << 14);
    const char* bs = lds + bsel + 32768 + ((wn >> 1) << 14) + ((wn & 1) << 13);
    bf16x8 a[8][2], b[4][2];

    // ---- phase 1: read all B + A rows 0-3; stage A1(T+1)
    ldB4<0>(b, bs, r16, quad, xr);
    ldA4<0>(a, as, r16, quad, xr);
    stage(T + 1, 1);
    HWBAR(); LGKM0(); SB();
    __builtin_amdgcn_s_setprio(1);
    qmfma<0, 0>(acc, a, b);
    __builtin_amdgcn_s_setprio(0);
    HWBAR();

    // ---- phase 2: read A rows 4-7; stage B0(T+2)
    ldA4<4>(a, as, r16, quad, xr);
    stage(T + 2, 2);
    HWBAR(); LGKM0(); SB();
    __builtin_amdgcn_s_setprio(1);
    qmfma<1, 0>(acc, a, b);
    __builtin_amdgcn_s_setprio(0);
    HWBAR();

    // ---- phase 3: stage B1(T+2)
    stage(T + 2, 3);
    HWBAR();
    __builtin_amdgcn_s_setprio(1);
    qmfma<0, 1>(acc, a, b);
    __builtin_amdgcn_s_setprio(0);
    HWBAR();

    // ---- phase 4: stage A0(T+2)
    stage(T + 2, 0);
    HWBAR();
    __builtin_amdgcn_s_setprio(1);
    qmfma<1, 1>(acc, a, b);
    __builtin_amdgcn_s_setprio(0);
    if (T + 2 < NT) { asm volatile("s_waitcnt vmcnt(6)" ::: "memory"); }
    else            { asm volatile("s_waitcnt vmcnt(0)" ::: "memory"); }
    SB();            // keep next tile's ds_reads/stages out of the vmcnt->barrier window
    HWBAR();
  }

  // ---- epilogue
  const long cbase = (long)ks * M * Nn;
  #pragma unroll
  for (int mf = 0; mf < 8; ++mf)
    #pragma unroll
    for (int nf = 0; nf < 4; ++nf) {
      long r0 = tm + wm * 128 + mf * 16 + quad * 4;
      long cc = tn + wn * 64 + nf * 16 + r16;
      if (cc < Nn) {
        #pragma unroll
        for (int reg = 0; reg < 4; ++reg) {
          long idx = (r0 + reg) * (long)Nn + cc;
          if (outf32) Cf[cbase + idx] = acc[mf][nf][reg];
          else        Cb[idx] = (bf16)acc[mf][nf][reg];
        }
      }
    }
}

// ---------------------------------------------------------------- split-K partial reduce (f32)
__global__ void addred_k(const float* __restrict__ P, float* __restrict__ out, long n4) {
  long i = (long)blockIdx.x * 256 + threadIdx.x;
  if (i >= n4) return;
  float4 a = ((const float4*)P)[i];
  float4 b = ((const float4*)P)[i + n4];
  float4 r; r.x = a.x + b.x; r.y = a.y + b.y; r.z = a.z + b.z; r.w = a.w + b.w;
  ((float4*)out)[i] = r;
}

// ---------------------------------------------------------------- depthwise causal conv + silu + split (+ B^T copy)
__global__ void conv_silu_k(const bf16* __restrict__ proj,
                            const float* __restrict__ conv_w,
                            const float* __restrict__ conv_b,
                            bf16* __restrict__ xconv,
                            bf16* __restrict__ Bmb, bf16* __restrict__ Cmb,
                            bf16* __restrict__ Bt)
{
  int ch = blockIdx.x * 256 + threadIdx.x;
  if (ch >= CONVD) return;
  long bl = blockIdx.y;
  int l = (int)(bl & (LQ - 1));
  float acc = conv_b[ch];
  #pragma unroll
  for (int t = 0; t < 4; ++t) {
    int ls = l - 3 + t;
    if (ls >= 0)
      acc += (float)proj[(bl - 3 + t) * PROJP + INTER + ch] * conv_w[ch * 4 + t];
  }
  float y = siluf(acc);
  if (ch < INTER) {
    xconv[bl * INTER + ch] = (bf16)y;
  } else if (ch < INTER + NS) {
    int n = ch - INTER;
    Bmb[bl * NS + n] = (bf16)y;
    int b = (int)(bl >> 11), ci = l >> 8, j = l & 255;
    Bt[(((long)(b * NC + ci) * NS) + n) * CS + j] = (bf16)y;
  } else {
    Cmb[bl * NS + (ch - INTER - NS)] = (bf16)y;
  }
}

// ---------------------------------------------------------------- dt softplus + per-chunk cumsum of dA
__global__ __launch_bounds__(CS) void dt_prep_k(
    const bf16* __restrict__ proj, const float* __restrict__ dt_bias,
    const float* __restrict__ A_log,
    float* __restrict__ dtv, float* __restrict__ acum, float* __restrict__ cdec)
{
  int bx = blockIdx.x;          // (b*NH + h)*NC + ci
  int ci = bx & 7;
  int bh = bx >> 3;
  int h  = bh & 63;
  int b  = bh >> 6;
  int i  = threadIdx.x;
  long pos = (long)b * LQ + ci * CS + i;
  float draw = (float)proj[pos * PROJP + INTER + CONVD + h] + dt_bias[h];
  float dv = draw > 20.f ? draw : log1pf(expf(draw));
  float Ah = -expf(A_log[h]);
  __shared__ float s[CS];
  s[i] = dv * Ah;
  __syncthreads();
  for (int off = 1; off < CS; off <<= 1) {
    float t = (i >= off) ? s[i - off] : 0.f;
    __syncthreads();
    s[i] += t;
    __syncthreads();
  }
  long base = (long)bx * CS;
  dtv[base + i]  = dv;
  acum[base + i] = s[i];
  if (i == 0) cdec[bx] = expf(s[CS - 1]);
}

// ---------------------------------------------------------------- G[i][j] = C_i . B_j via MFMA (G=1, head-independent)
__global__ __launch_bounds__(256) void gmat_k(
    const bf16* __restrict__ Cmb, const bf16* __restrict__ Bmb, float* __restrict__ Gnt)
{
  int q  = blockIdx.x;              // quadrant: ti=q>>1, tj=q&1 (128x128 each)
  int bc = blockIdx.y;              // b*NC + ci
  long bl0 = (long)(bc >> 3) * LQ + (bc & 7) * CS;
  int wave = threadIdx.x >> 6, lane = threadIdx.x & 63;
  int quad = lane >> 4, r16 = lane & 15;
  int i0 = (q >> 1) * 128 + (wave >> 1) * 64;
  int j0 = (q & 1)  * 128 + (wave & 1)  * 64;

  f32x4 acc[4][4] = {};
  #pragma unroll
  for (int kt = 0; kt < 4; ++kt) {
    int k0 = kt * 32 + quad * 8;
    bf16x8 af[4], bfv[4];
    #pragma unroll
    for (int it = 0; it < 4; ++it)
      af[it] = *(const bf16x8*)&Cmb[(bl0 + i0 + it * 16 + r16) * NS + k0];
    #pragma unroll
    for (int nt = 0; nt < 4; ++nt)
      bfv[nt] = *(const bf16x8*)&Bmb[(bl0 + j0 + nt * 16 + r16) * NS + k0];
    #pragma unroll
    for (int it = 0; it < 4; ++it)
      #pragma unroll
      for (int nt = 0; nt < 4; ++nt)
        acc[it][nt] = __builtin_amdgcn_mfma_f32_16x16x32_bf16(af[it], bfv[nt], acc[it][nt], 0, 0, 0);
  }
  #pragma unroll
  for (int it = 0; it < 4; ++it)
    #pragma unroll
    for (int nt = 0; nt < 4; ++nt)
      #pragma unroll
      for (int reg = 0; reg < 4; ++reg) {
        int i = i0 + it * 16 + quad * 4 + reg;
        int j = j0 + nt * 16 + r16;
        Gnt[((long)bc * CS + i) * CS + j] = acc[it][nt][reg];
      }
}

// ---------------------------------------------------------------- chunk states via MFMA: state[p][n] = sum_j (X[j][p]*w_j)*B[j][n]
__global__ __launch_bounds__(256) void states_k(
    const bf16* __restrict__ xconv, const bf16* __restrict__ Bt,
    const float* __restrict__ dtv, const float* __restrict__ acum,
    bf16* __restrict__ st)
{
  int bx = blockIdx.x;          // bc*NH + h
  int h = bx & 63, bc = bx >> 6;
  int b = bc >> 3, ci = bc & 7;
  long bl0 = (long)b * LQ + ci * CS;
  long abase = ((long)(b * NH + h) * NC + ci) * CS;
  int t = threadIdx.x;
  int wave = t >> 6, lane = t & 63, quad = lane >> 4, r16 = lane & 15;

  __shared__ bf16 Xt[64][264];
  __shared__ float ws[CS];
  __shared__ float ac_s[CS];
  ac_s[t] = acum[abase + t];
  __syncthreads();
  float alast = ac_s[CS - 1];
  ws[t] = expf(alast - ac_s[t]) * dtv[abase + t];
  // stage X^T (coalesced: lanes span p)
  {
    int col = t & 63, grp = t >> 6;
    for (int r = 0; r < 64; ++r) {
      int j = grp * 64 + r;
      Xt[col][j] = xconv[(bl0 + j) * INTER + h * HD + col];
    }
  }
  __syncthreads();

  const bf16* btb = &Bt[(long)bc * NS * CS];
  f32x4 acc[8] = {};
  int p = wave * 16 + r16;
  #pragma unroll
  for (int kt = 0; kt < 8; ++kt) {
    int k0 = kt * 32 + quad * 8;
    bf16x8 xv = *(const bf16x8*)&Xt[p][k0];
    float w8[8];
    *(float4*)&w8[0] = *(const float4*)&ws[k0];
    *(float4*)&w8[4] = *(const float4*)&ws[k0 + 4];
    bf16x8 af;
    #pragma unroll
    for (int jj = 0; jj < 8; ++jj) af[jj] = (bf16)((float)xv[jj] * w8[jj]);
    #pragma unroll
    for (int nt = 0; nt < 8; ++nt) {
      bf16x8 bfv = *(const bf16x8*)&btb[(nt * 16 + r16) * CS + k0];
      acc[nt] = __builtin_amdgcn_mfma_f32_16x16x32_bf16(af, bfv, acc[nt], 0, 0, 0);
    }
  }
  #pragma unroll
  for (int nt = 0; nt < 8; ++nt)
    #pragma unroll
    for (int reg = 0; reg < 4; ++reg) {
      int prow = wave * 16 + quad * 4 + reg;
      int n = nt * 16 + r16;
      st[((long)bx * HD + prow) * NS + n] = (bf16)acc[nt][reg];
    }
}

// ---------------------------------------------------------------- inter-chunk scan, IN PLACE (st -> prev)
__global__ void scan_k(bf16* __restrict__ st, const float* __restrict__ cdec)
{
  long t = (long)blockIdx.x * 256 + threadIdx.x;  // (b,h,p,n)
  int n = (int)(t & 127);
  int p = (int)((t >> 7) & 63);
  int h = (int)((t >> 13) & 63);
  int b = (int)(t >> 19);
  float carry = 0.f;
  for (int ci = 0; ci < NC; ++ci) {
    long idx = (((long)(b * NC + ci) * NH + h) * HD + p) * NS + n;
    float v = (float)st[idx];
    st[idx] = (bf16)carry;
    carry = cdec[(b * NH + h) * NC + ci] * carry + v;
  }
}

// ---------------------------------------------------------------- fused Ydiag+Yoff+D*x via MFMA  (Y aliases xconv)
#define XTP 392   /* padded row length (bf16) for Xt: 384+8, keeps 16B alignment */
__global__ __launch_bounds__(256) void ymix_k(
    const bf16* __restrict__ xconv, const float* __restrict__ Gnt,
    const bf16* __restrict__ prev, const bf16* __restrict__ Cmb,
    const float* __restrict__ dtv, const float* __restrict__ acum,
    const float* __restrict__ Dp, bf16* __restrict__ Y)
{
  int bx = blockIdx.x;          // bc*NH + h
  int h = bx & 63, bc = bx >> 6;
  int b = bc >> 3, ci = bc & 7;
  long bl0 = (long)b * LQ + ci * CS;
  long abase = ((long)(b * NH + h) * NC + ci) * CS;
  int t = threadIdx.x;
  int wave = t >> 6, lane = t & 63;
  int quad = lane >> 4, r16 = lane & 15;
  int iw = wave * 64;

  __shared__ bf16 Xt[64][XTP];          // [p][k]: k<256 = X^T, k>=256 = prev^T
  __shared__ float a2s[CS], dts[CS], eas[CS];

  {
    float ac = acum[abase + t];
    a2s[t] = ac * LOG2E;
    dts[t] = dtv[abase + t];
    eas[t] = expf(ac);
  }
  {
    int col = t & 63, grp = t >> 6;
    for (int r = 0; r < 64; ++r) {
      int j = grp * 64 + r;
      Xt[col][j] = xconv[(bl0 + j) * INTER + h * HD + col];
    }
  }
  for (int r = 0; r < 32; ++r) {
    int idx = t + r * 256;
    int n = idx & 127, p = idx >> 7;
    Xt[p][256 + n] = prev[((long)bx * HD + p) * NS + n];
  }
  __syncthreads();

  f32x4 acc[4][4] = {};

  for (int kt = 0; kt < 12; ++kt) {
    int k0 = kt * 32;
    bool cpart = (k0 >= 256);
    if (!cpart && k0 > iw + 63) continue;   // whole k-tile above diagonal for this wave

    bf16x8 bfrag[4];
    #pragma unroll
    for (int nt = 0; nt < 4; ++nt)
      bfrag[nt] = *(const bf16x8*)&Xt[nt * 16 + r16][k0 + quad * 8];

    if (!cpart) {
      int j0 = k0 + quad * 8;
      float dt8[8], a28[8];
      *(float4*)&dt8[0] = *(const float4*)&dts[j0];
      *(float4*)&dt8[4] = *(const float4*)&dts[j0 + 4];
      *(float4*)&a28[0] = *(const float4*)&a2s[j0];
      *(float4*)&a28[4] = *(const float4*)&a2s[j0 + 4];
      #pragma unroll
      for (int it = 0; it < 4; ++it) {
        if (k0 > iw + it * 16 + 15) continue;   // zero tile
        int i = iw + it * 16 + r16;
        float a2i = a2s[i];
        const float* gp = &Gnt[((long)bc * CS + i) * CS + j0];
        float g[8];
        *(float4*)&g[0] = *(const float4*)gp;
        *(float4*)&g[4] = *(const float4*)(gp + 4);
        bf16x8 af;
        #pragma unroll
        for (int jj = 0; jj < 8; ++jj) {
          float v = g[jj] * dt8[jj] * exp2f(a2i - a28[jj]);
          v = (j0 + jj <= i) ? v : 0.f;
          af[jj] = (bf16)v;
        }
        #pragma unroll
        for (int nt = 0; nt < 4; ++nt)
          acc[it][nt] = __builtin_amdgcn_mfma_f32_16x16x32_bf16(af, bfrag[nt], acc[it][nt], 0, 0, 0);
      }
    } else {
      int n0 = k0 - 256 + quad * 8;
      #pragma unroll
      for (int it = 0; it < 4; ++it) {
        int i = iw + it * 16 + r16;
        float e = eas[i];
        bf16x8 cv = *(const bf16x8*)&Cmb[(bl0 + i) * NS + n0];
        bf16x8 af;
        #pragma unroll
        for (int jj = 0; jj < 8; ++jj)
          af[jj] = (bf16)(e * (float)cv[jj]);
        #pragma unroll
        for (int nt = 0; nt < 4; ++nt)
          acc[it][nt] = __builtin_amdgcn_mfma_f32_16x16x32_bf16(af, bfrag[nt], acc[it][nt], 0, 0, 0);
      }
    }
  }

  float Dh = Dp[h];
  #pragma unroll
  for (int it = 0; it < 4; ++it)
    #pragma unroll
    for (int nt = 0; nt < 4; ++nt) {
      int i0 = iw + it * 16 + quad * 4;
      int p  = nt * 16 + r16;
      bf16x4 xv = *(const bf16x4*)&Xt[p][i0];
      #pragma unroll
      for (int reg = 0; reg < 4; ++reg) {
        float v = acc[it][nt][reg] + Dh * (float)xv[reg];
        Y[(bl0 + i0 + reg) * INTER + h * HD + p] = (bf16)v;
      }
    }
}

// ---------------------------------------------------------------- gate*silu + RMS norm, IN PLACE
__global__ __launch_bounds__(256) void norm_k(
    bf16* __restrict__ Y, const bf16* __restrict__ proj,
    const float* __restrict__ norm_w)
{
  long bl = blockIdx.x;
  int t = threadIdx.x;
  __shared__ float yb[INTER];
  __shared__ float red[256];
  float ss = 0.f;
  for (int r = 0; r < 16; ++r) {
    int ch = t + r * 256;
    float g = (float)proj[bl * PROJP + ch];
    float yv = (float)Y[bl * INTER + ch] * siluf(g);
    yb[ch] = yv;
    ss += yv * yv;
  }
  red[t] = ss;
  __syncthreads();
  for (int s = 128; s > 0; s >>= 1) {
    if (t < s) red[t] += red[t + s];
    __syncthreads();
  }
  float scale = rsqrtf(red[0] / (float)INTER + EPSF);
  for (int r = 0; r < 16; ++r) {
    int ch = t + r * 256;
    Y[bl * INTER + ch] = (bf16)(yb[ch] * scale * norm_w[ch]);
  }
}

// ---------------------------------------------------------------- launch
extern "C" void kernel_launch(void* const* d_in, const int* in_sizes, int n_in,
                              void* d_out, int out_size, void* d_ws, size_t ws_size,
                              hipStream_t stream)
{
  (void)in_sizes; (void)n_in; (void)out_size; (void)ws_size;
  const float* hidden  = (const float*)d_in[0];
  const float* W_in    = (const float*)d_in[1];
  const float* conv_w  = (const float*)d_in[2];
  const float* conv_b  = (const float*)d_in[3];
  const float* dt_bias = (const float*)d_in[4];
  const float* A_log   = (const float*)d_in[5];
  const float* Dp      = (const float*)d_in[6];
  const float* norm_w  = (const float*)d_in[7];
  const float* W_out   = (const float*)d_in[8];
  float* out = (float*)d_out;

  // ---- workspace layout with lifetime-based aliasing (peak ~124.7 MiB)
  char* ws    = (char*)d_ws;
  bf16* projb = (bf16*)(ws);                         // 70,254,592  [gemm1 .. norm]; then f32 split-K partials (67.1 MB)
  char* base2 = ws + 70254592;
  bf16*  hb    = (bf16*)(base2);                     // 16,777,216  [stage1 only]
  bf16*  winb  = (bf16*)(base2 + 16777216);          // 35,651,584  [stage1 only] (PROJW rows)
  bf16*  xconv = (bf16*)(base2);                     // 33,554,432  [conv .. ymix] = Y
  bf16*  st    = (bf16*)(base2 + 33554432);          // 16,777,216  [states .. ymix]
  float* Gnt   = (float*)(base2 + 50331648);         //  4,194,304
  bf16*  Bmb   = (bf16*)(base2 + 54525952);          //  1,048,576
  bf16*  Cmb   = (bf16*)(base2 + 55574528);          //  1,048,576
  float* dtv   = (float*)(base2 + 56623104);         //  1,048,576
  float* acum  = (float*)(base2 + 57671680);         //  1,048,576
  float* cdec  = (float*)(base2 + 58720256);         //      4,096
  bf16*  Bt    = (bf16*)(base2 + 58724352);          //  1,048,576 (B transposed per chunk)
  bf16*  Yb    = xconv;                              // alias (disjoint per-block tiles)
  bf16*  woutb = st;                                 // alias st (dead after ymix), exact 16 MiB

  // stage 1: casts + in-projection GEMM (8-phase 256^2, store-predicated to Nn=PROJP)
  cast4_k<<<dim3((unsigned)((MTOT * (long)DMODEL / 4 + 255) / 256)), 256, 0, stream>>>(
      hidden, hb, (long)MTOT * DMODEL / 4);
  cast_pad_win_k<<<dim3((unsigned)(((long)PROJW * (DMODEL / 4) + 255) / 256)), 256, 0, stream>>>(
      W_in, winb);
  gemm8<<<dim3((PROJW / 256) * (MTOT / 256)), 512, 0, stream>>>(
      hb, winb, projb, nullptr, MTOT, PROJP, PROJW / 256, DMODEL, 1, 0);

  // stage 2: conv + SSD
  conv_silu_k<<<dim3(CONVD / 256, MTOT), 256, 0, stream>>>(
      projb, conv_w, conv_b, xconv, Bmb, Cmb, Bt);
  dt_prep_k<<<dim3(BQ * NH * NC), CS, 0, stream>>>(
      projb, dt_bias, A_log, dtv, acum, cdec);
  gmat_k<<<dim3(4, BQ * NC), 256, 0, stream>>>(Cmb, Bmb, Gnt);
  states_k<<<dim3(BQ * NC * NH), 256, 0, stream>>>(xconv, Bt, dtv, acum, st);
  scan_k<<<dim3(BQ * NH * HD * NS / 256), 256, 0, stream>>>(st, cdec);
  ymix_k<<<dim3(BQ * NC * NH), 256, 0, stream>>>(
      xconv, Gnt, st, Cmb, dtv, acum, Dp, Yb);

  // stage 3: norm + out-projection GEMM (8-phase, split-K=2 into f32 partials, then reduce)
  cast4_k<<<dim3((unsigned)((DMODEL * (long)INTER / 4 + 255) / 256)), 256, 0, stream>>>(
      W_out, woutb, (long)DMODEL * INTER / 4);
  norm_k<<<dim3(MTOT), 256, 0, stream>>>(Yb, projb, norm_w);
  gemm8<<<dim3((DMODEL / 256) * (MTOT / 256) * 2), 512, 0, stream>>>(
      Yb, woutb, nullptr, (float*)projb, MTOT, DMODEL, DMODEL / 256, INTER, 2, 1);
  addred_k<<<dim3((unsigned)((MTOT * (long)DMODEL / 4 + 255) / 256)), 256, 0, stream>>>(
      (const float*)projb, out, (long)MTOT * DMODEL / 4);
}

// Round 5
// 644.230 us; speedup vs baseline: 1.0367x; 1.0367x over previous
//
#include <hip/hip_runtime.h>
#include <cstdint>

typedef __bf16 bf16;
typedef __bf16 bf16x8 __attribute__((ext_vector_type(8)));
typedef __bf16 bf16x4 __attribute__((ext_vector_type(4)));
typedef float  f32x4  __attribute__((ext_vector_type(4)));

#define BQ     2
#define LQ     2048
#define DMODEL 2048
#define INTER  4096
#define NH     64
#define HD     64
#define NS     128
#define CS     256
#define NC     8
#define CONVD  4352
#define PROJD  8512
#define PROJP  8576   /* padded proj stride (128-multiple) */
#define PROJW  8704   /* W_in rows padded to 256-multiple for 256-wide GEMM tiles */
#define MTOT   4096   /* B*L */
#define EPSF   1e-5f
#define LOG2E  1.44269504088896f

// ---------------------------------------------------------------- utilities
__device__ __forceinline__ void async_ld16(const bf16* g, bf16* l) {
  __builtin_amdgcn_global_load_lds(
      (__attribute__((address_space(1))) void*)(uintptr_t)g,
      (__attribute__((address_space(3))) void*)l, 16, 0, 0);
}

__device__ __forceinline__ float siluf(float x) { return x / (1.f + expf(-x)); }

#define SB()    __builtin_amdgcn_sched_barrier(0)
#define HWBAR() __builtin_amdgcn_s_barrier()

// ---------------------------------------------------------------- casts
__global__ void cast4_k(const float* __restrict__ in, bf16* __restrict__ out, long n4) {
  long i = (long)blockIdx.x * 256 + threadIdx.x;
  if (i >= n4) return;
  float4 v = ((const float4*)in)[i];
  bf16x4 o; o[0] = (bf16)v.x; o[1] = (bf16)v.y; o[2] = (bf16)v.z; o[3] = (bf16)v.w;
  ((bf16x4*)out)[i] = o;
}

__global__ void cast_pad_win_k(const float* __restrict__ W, bf16* __restrict__ out) {
  long i = (long)blockIdx.x * 256 + threadIdx.x;       // over PROJW * (DMODEL/4)
  long tot = (long)PROJW * (DMODEL / 4);
  if (i >= tot) return;
  long row = i / (DMODEL / 4);
  long k4  = i % (DMODEL / 4);
  bf16x4 o;
  if (row < PROJD) {
    float4 v = ((const float4*)W)[row * (DMODEL / 4) + k4];
    o[0] = (bf16)v.x; o[1] = (bf16)v.y; o[2] = (bf16)v.z; o[3] = (bf16)v.w;
  } else {
    o[0] = o[1] = o[2] = o[3] = (bf16)0.f;
  }
  ((bf16x4*)out)[i] = o;
}

// ---------------------------------------------------------------- 256x256 GEMM  C = A(MxK) * W(NxK)^T
// 8 waves (2M x 4N), BK=64. LDS = 2 buffers x 64 KiB; per buffer:
//   part 0 = A[0:128), part 1 = A[128:256), part 2 = B[0:128), part 3 = B[128:256)
// global_load_lds x16B, linear LDS dest, XOR-8 pre-swizzled global source;
// read: 16B-group g of row r at physical group g^(r&7) (conflict-free ds_read_b128).
//
// Pipelined 4-region tile loop (reads issue 1-3 regions AHEAD of their MFMA; no asm
// lgkmcnt — compiler inserts counted waits at each MFMA, so operand drain overlaps
// the previous MFMA cluster):
//   R1: stage p01(T+1)[other buf]; read b1(T)[4], a1(T)[8]          | barA
//   R2: MFMA q(m0,n0) <- a0,b0   (read in R4 of T-1)                 | barB
//   R3: MFMA q(m0,n1) <- a0,b1 ; vmcnt(0)                            | barC
//   R4: MFMA q(m1,n0)+q(m1,n1) <- a1,b0/b1 ; read a0'(T+1)[8],
//       b0'(T+1)[4] (other buf); stage p23(T+2)[same buf]            | barD
// Slot-liveness (compiler-wait aware): parts01(T-1) reads (a1(T-1)) drain pre-MFMA3,
// i.e. before barD(T-1)  -> stage p01(T+1) at R1(T) is 1 barrier later: safe.
// parts23(T) reads (b1(T)) drain pre-MFMA2 < barC(T) -> stage p23(T+2) in R4(T): safe.
// vmcnt(0) at R3(T) + barC orders: p01(T+1) [staged R1(T), A-panel=L2-hot] and
// p23(T+1) [staged R4(T-1), ~3.5 regions lead] before R4(T)'s reads of buffer T+1.
// WAR: R4 reads overwrite a0 (last use MFMA2) and b0 (last use MFMA3, same region,
// program order) -> legal; register footprint unchanged (96 operand VGPRs).

template<int MH>   // a-half: frags mf = MH*4 + {0..3}  (rows MH*64 .. +63 of the part)
__device__ __forceinline__ void ldAh(bf16x8 (&dst)[4][2], const char* base,
                                     int r16, int quad, int xr) {
  #pragma unroll
  for (int f = 0; f < 4; ++f)
    #pragma unroll
    for (int kk = 0; kk < 2; ++kk)
      dst[f][kk] = *(const bf16x8*)(base + ((((MH * 4 + f) * 16) + r16) << 7)
                                         + ((((kk << 2) + quad) ^ xr) << 4));
}

template<int NH2>  // b-half: frags nf = NH2*2 + {0,1}  (cols NH2*32 .. +31 of wave slice)
__device__ __forceinline__ void ldBh(bf16x8 (&dst)[2][2], const char* base,
                                     int r16, int quad, int xr) {
  #pragma unroll
  for (int f = 0; f < 2; ++f)
    #pragma unroll
    for (int kk = 0; kk < 2; ++kk)
      dst[f][kk] = *(const bf16x8*)(base + ((((NH2 * 2 + f) * 16) + r16) << 7)
                                         + ((((kk << 2) + quad) ^ xr) << 4));
}

template<int MH, int NH2>
__device__ __forceinline__ void qmfma(f32x4 (&acc)[8][4], const bf16x8 (&a)[4][2],
                                      const bf16x8 (&b)[2][2]) {
  // mm fastest: consecutive MFMAs never share an accumulator
  #pragma unroll
  for (int kk = 0; kk < 2; ++kk)
    #pragma unroll
    for (int nf = 0; nf < 2; ++nf)
      #pragma unroll
      for (int mm = 0; mm < 4; ++mm)
        acc[MH * 4 + mm][NH2 * 2 + nf] = __builtin_amdgcn_mfma_f32_16x16x32_bf16(
            a[mm][kk], b[nf][kk], acc[MH * 4 + mm][NH2 * 2 + nf], 0, 0, 0);
}

__global__ __launch_bounds__(512, 2) void gemm8(
    const bf16* __restrict__ A, const bf16* __restrict__ W,
    bf16* __restrict__ Cb, float* __restrict__ Cf,
    int M, int Nn, int Ntiles, int K, int KS, int outf32)
{
  __shared__ int4 lds4[8192];            // 128 KiB
  char* lds = (char*)lds4;
  const int tid  = threadIdx.x;
  const int w    = tid >> 6;
  const int l    = tid & 63;
  const int wm   = w >> 2;               // 0..1
  const int wn   = w & 3;                // 0..3
  const int quad = l >> 4;
  const int r16  = l & 15;
  const int xr   = r16 & 7;

  const int Mtiles  = M >> 8;
  const int tilesMN = Mtiles * Ntiles;
  const int nwg = tilesMN * KS;
  int bid = blockIdx.x;
  int sid = ((nwg & 7) == 0) ? ((bid & 7) * (nwg >> 3) + (bid >> 3)) : bid;
  const int ks  = sid / tilesMN;
  const int rem = sid - ks * tilesMN;
  const int by = rem % Mtiles;
  const int bx = rem / Mtiles;
  const long tm = (long)by << 8;
  const long tn = (long)bx << 8;
  const int  NT = K / (64 * KS);
  const long kbase = (long)ks * (K / KS);

  // staging lane coords (round = 64 rows; lane covers 16B at swizzled k-group)
  const int srow = w * 8 + (l >> 3);
  const int scg  = (l & 7) ^ ((l >> 3) & 7);
  const bf16* Ab = A + (tm + srow) * K + kbase + scg * 8;
  const bf16* Wb = W + (tn + srow) * K + kbase + scg * 8;

  auto stage = [&](int tile, int part) {
    if (tile < NT) {
      const bf16* s = (part < 2 ? Ab : Wb) + (long)((part & 1) * 128) * K + (long)tile * 64;
      char* d = lds + ((tile & 1) << 16) + (part << 14) + (w << 10);
      async_ld16(s, (bf16*)d);
      async_ld16(s + (long)K * 64, (bf16*)(d + 8192));
    }
  };

  // ---- prologue: tile0 all parts + tile1 B-parts; p01(1) is staged in R1 of T=0.
  stage(0, 0); stage(0, 1); stage(0, 2); stage(0, 3);
  stage(1, 2); stage(1, 3);
  asm volatile("s_waitcnt vmcnt(4)" ::: "memory");   // tile0 landed; p23(1) in flight
  SB();
  HWBAR();
  SB();

  bf16x8 a0[4][2], a1[4][2], b0[2][2], b1[2][2];
  {
    const char* as0 = lds + (wm << 14);
    const char* bs0 = lds + 32768 + ((wn >> 1) << 14) + ((wn & 1) << 13);
    ldAh<0>(a0, as0, r16, quad, xr);
    ldBh<0>(b0, bs0, r16, quad, xr);
  }

  f32x4 acc[8][4] = {};

  for (int T = 0; T < NT; ++T) {
    const int bsel  = (T & 1) << 16;
    const char* as  = lds + bsel + (wm << 14);
    const char* bs  = lds + bsel + 32768 + ((wn >> 1) << 14) + ((wn & 1) << 13);
    const char* asN = lds + (bsel ^ 0x10000) + (wm << 14);
    const char* bsN = lds + (bsel ^ 0x10000) + 32768 + ((wn >> 1) << 14) + ((wn & 1) << 13);

    // ---- R1: stage next A panel (other buffer); read b1,a1 of current tile
    SB();
    stage(T + 1, 0); stage(T + 1, 1);
    ldBh<1>(b1, bs, r16, quad, xr);          // 4 reads (used at MFMA2)
    ldAh<1>(a1, as, r16, quad, xr);          // 8 reads (used at MFMA3/4)
    SB(); HWBAR(); SB();                     // barA

    // ---- R2
    __builtin_amdgcn_s_setprio(1);
    qmfma<0, 0>(acc, a0, b0);                // MFMA1 (m0,n0)
    __builtin_amdgcn_s_setprio(0);
    SB(); HWBAR(); SB();                     // barB

    // ---- R3
    __builtin_amdgcn_s_setprio(1);
    qmfma<0, 1>(acc, a0, b1);                // MFMA2 (m0,n1)
    __builtin_amdgcn_s_setprio(0);
    asm volatile("s_waitcnt vmcnt(0)" ::: "memory");  // p01(T+1) + p23(T+1) landed
    SB(); HWBAR(); SB();                     // barC

    // ---- R4
    __builtin_amdgcn_s_setprio(1);
    qmfma<1, 0>(acc, a1, b0);                // MFMA3 (m1,n0)
    qmfma<1, 1>(acc, a1, b1);                // MFMA4 (m1,n1)
    __builtin_amdgcn_s_setprio(0);
    ldAh<0>(a0, asN, r16, quad, xr);         // 8 reads: a0 of T+1 (WAR: a0 free after MFMA2)
    ldBh<0>(b0, bsN, r16, quad, xr);         // 4 reads: b0 of T+1 (WAR: b0 free after MFMA3)
    stage(T + 2, 2); stage(T + 2, 3);        // next B panel (same buffer as T)
    SB(); HWBAR();                           // barD
  }
  asm volatile("s_waitcnt vmcnt(0)" ::: "memory");  // no DMA in flight at endpgm

  // ---- epilogue
  const long cbase = (long)ks * M * Nn;
  #pragma unroll
  for (int mf = 0; mf < 8; ++mf)
    #pragma unroll
    for (int nf = 0; nf < 4; ++nf) {
      long r0 = tm + wm * 128 + mf * 16 + quad * 4;
      long cc = tn + wn * 64 + nf * 16 + r16;
      if (cc < Nn) {
        #pragma unroll
        for (int reg = 0; reg < 4; ++reg) {
          long idx = (r0 + reg) * (long)Nn + cc;
          if (outf32) Cf[cbase + idx] = acc[mf][nf][reg];
          else        Cb[idx] = (bf16)acc[mf][nf][reg];
        }
      }
    }
}

// ---------------------------------------------------------------- split-K partial reduce (f32)
__global__ void addred_k(const float* __restrict__ P, float* __restrict__ out, long n4) {
  long i = (long)blockIdx.x * 256 + threadIdx.x;
  if (i >= n4) return;
  float4 a = ((const float4*)P)[i];
  float4 b = ((const float4*)P)[i + n4];
  float4 r; r.x = a.x + b.x; r.y = a.y + b.y; r.z = a.z + b.z; r.w = a.w + b.w;
  ((float4*)out)[i] = r;
}

// ---------------------------------------------------------------- depthwise causal conv + silu + split (+ B^T copy)
__global__ void conv_silu_k(const bf16* __restrict__ proj,
                            const float* __restrict__ conv_w,
                            const float* __restrict__ conv_b,
                            bf16* __restrict__ xconv,
                            bf16* __restrict__ Bmb, bf16* __restrict__ Cmb,
                            bf16* __restrict__ Bt)
{
  int ch = blockIdx.x * 256 + threadIdx.x;
  if (ch >= CONVD) return;
  long bl = blockIdx.y;
  int l = (int)(bl & (LQ - 1));
  float acc = conv_b[ch];
  #pragma unroll
  for (int t = 0; t < 4; ++t) {
    int ls = l - 3 + t;
    if (ls >= 0)
      acc += (float)proj[(bl - 3 + t) * PROJP + INTER + ch] * conv_w[ch * 4 + t];
  }
  float y = siluf(acc);
  if (ch < INTER) {
    xconv[bl * INTER + ch] = (bf16)y;
  } else if (ch < INTER + NS) {
    int n = ch - INTER;
    Bmb[bl * NS + n] = (bf16)y;
    int b = (int)(bl >> 11), ci = l >> 8, j = l & 255;
    Bt[(((long)(b * NC + ci) * NS) + n) * CS + j] = (bf16)y;
  } else {
    Cmb[bl * NS + (ch - INTER - NS)] = (bf16)y;
  }
}

// ---------------------------------------------------------------- dt softplus + per-chunk cumsum of dA
__global__ __launch_bounds__(CS) void dt_prep_k(
    const bf16* __restrict__ proj, const float* __restrict__ dt_bias,
    const float* __restrict__ A_log,
    float* __restrict__ dtv, float* __restrict__ acum, float* __restrict__ cdec)
{
  int bx = blockIdx.x;          // (b*NH + h)*NC + ci
  int ci = bx & 7;
  int bh = bx >> 3;
  int h  = bh & 63;
  int b  = bh >> 6;
  int i  = threadIdx.x;
  long pos = (long)b * LQ + ci * CS + i;
  float draw = (float)proj[pos * PROJP + INTER + CONVD + h] + dt_bias[h];
  float dv = draw > 20.f ? draw : log1pf(expf(draw));
  float Ah = -expf(A_log[h]);
  __shared__ float s[CS];
  s[i] = dv * Ah;
  __syncthreads();
  for (int off = 1; off < CS; off <<= 1) {
    float t = (i >= off) ? s[i - off] : 0.f;
    __syncthreads();
    s[i] += t;
    __syncthreads();
  }
  long base = (long)bx * CS;
  dtv[base + i]  = dv;
  acum[base + i] = s[i];
  if (i == 0) cdec[bx] = expf(s[CS - 1]);
}

// ---------------------------------------------------------------- G[i][j] = C_i . B_j via MFMA (G=1, head-independent)
__global__ __launch_bounds__(256) void gmat_k(
    const bf16* __restrict__ Cmb, const bf16* __restrict__ Bmb, float* __restrict__ Gnt)
{
  int q  = blockIdx.x;              // quadrant: ti=q>>1, tj=q&1 (128x128 each)
  int bc = blockIdx.y;              // b*NC + ci
  long bl0 = (long)(bc >> 3) * LQ + (bc & 7) * CS;
  int wave = threadIdx.x >> 6, lane = threadIdx.x & 63;
  int quad = lane >> 4, r16 = lane & 15;
  int i0 = (q >> 1) * 128 + (wave >> 1) * 64;
  int j0 = (q & 1)  * 128 + (wave & 1)  * 64;

  f32x4 acc[4][4] = {};
  #pragma unroll
  for (int kt = 0; kt < 4; ++kt) {
    int k0 = kt * 32 + quad * 8;
    bf16x8 af[4], bfv[4];
    #pragma unroll
    for (int it = 0; it < 4; ++it)
      af[it] = *(const bf16x8*)&Cmb[(bl0 + i0 + it * 16 + r16) * NS + k0];
    #pragma unroll
    for (int nt = 0; nt < 4; ++nt)
      bfv[nt] = *(const bf16x8*)&Bmb[(bl0 + j0 + nt * 16 + r16) * NS + k0];
    #pragma unroll
    for (int it = 0; it < 4; ++it)
      #pragma unroll
      for (int nt = 0; nt < 4; ++nt)
        acc[it][nt] = __builtin_amdgcn_mfma_f32_16x16x32_bf16(af[it], bfv[nt], acc[it][nt], 0, 0, 0);
  }
  #pragma unroll
  for (int it = 0; it < 4; ++it)
    #pragma unroll
    for (int nt = 0; nt < 4; ++nt)
      #pragma unroll
      for (int reg = 0; reg < 4; ++reg) {
        int i = i0 + it * 16 + quad * 4 + reg;
        int j = j0 + nt * 16 + r16;
        Gnt[((long)bc * CS + i) * CS + j] = acc[it][nt][reg];
      }
}

// ---------------------------------------------------------------- chunk states via MFMA: state[p][n] = sum_j (X[j][p]*w_j)*B[j][n]
__global__ __launch_bounds__(256) void states_k(
    const bf16* __restrict__ xconv, const bf16* __restrict__ Bt,
    const float* __restrict__ dtv, const float* __restrict__ acum,
    bf16* __restrict__ st)
{
  int bx = blockIdx.x;          // bc*NH + h
  int h = bx & 63, bc = bx >> 6;
  int b = bc >> 3, ci = bc & 7;
  long bl0 = (long)b * LQ + ci * CS;
  long abase = ((long)(b * NH + h) * NC + ci) * CS;
  int t = threadIdx.x;
  int wave = t >> 6, lane = t & 63, quad = lane >> 4, r16 = lane & 15;

  __shared__ bf16 Xt[64][264];
  __shared__ float ws[CS];
  __shared__ float ac_s[CS];
  ac_s[t] = acum[abase + t];
  __syncthreads();
  float alast = ac_s[CS - 1];
  ws[t] = expf(alast - ac_s[t]) * dtv[abase + t];
  // stage X^T (coalesced: lanes span p)
  {
    int col = t & 63, grp = t >> 6;
    for (int r = 0; r < 64; ++r) {
      int j = grp * 64 + r;
      Xt[col][j] = xconv[(bl0 + j) * INTER + h * HD + col];
    }
  }
  __syncthreads();

  const bf16* btb = &Bt[(long)bc * NS * CS];
  f32x4 acc[8] = {};
  int p = wave * 16 + r16;
  #pragma unroll
  for (int kt = 0; kt < 8; ++kt) {
    int k0 = kt * 32 + quad * 8;
    bf16x8 xv = *(const bf16x8*)&Xt[p][k0];
    float w8[8];
    *(float4*)&w8[0] = *(const float4*)&ws[k0];
    *(float4*)&w8[4] = *(const float4*)&ws[k0 + 4];
    bf16x8 af;
    #pragma unroll
    for (int jj = 0; jj < 8; ++jj) af[jj] = (bf16)((float)xv[jj] * w8[jj]);
    #pragma unroll
    for (int nt = 0; nt < 8; ++nt) {
      bf16x8 bfv = *(const bf16x8*)&btb[(nt * 16 + r16) * CS + k0];
      acc[nt] = __builtin_amdgcn_mfma_f32_16x16x32_bf16(af, bfv, acc[nt], 0, 0, 0);
    }
  }
  #pragma unroll
  for (int nt = 0; nt < 8; ++nt)
    #pragma unroll
    for (int reg = 0; reg < 4; ++reg) {
      int prow = wave * 16 + quad * 4 + reg;
      int n = nt * 16 + r16;
      st[((long)bx * HD + prow) * NS + n] = (bf16)acc[nt][reg];
    }
}

// ---------------------------------------------------------------- inter-chunk scan, IN PLACE (st -> prev)
__global__ void scan_k(bf16* __restrict__ st, const float* __restrict__ cdec)
{
  long t = (long)blockIdx.x * 256 + threadIdx.x;  // (b,h,p,n)
  int n = (int)(t & 127);
  int p = (int)((t >> 7) & 63);
  int h = (int)((t >> 13) & 63);
  int b = (int)(t >> 19);
  float carry = 0.f;
  for (int ci = 0; ci < NC; ++ci) {
    long idx = (((long)(b * NC + ci) * NH + h) * HD + p) * NS + n;
    float v = (float)st[idx];
    st[idx] = (bf16)carry;
    carry = cdec[(b * NH + h) * NC + ci] * carry + v;
  }
}

// ---------------------------------------------------------------- fused Ydiag+Yoff+D*x via MFMA  (Y aliases xconv)
#define XTP 392   /* padded row length (bf16) for Xt: 384+8, keeps 16B alignment */
__global__ __launch_bounds__(256) void ymix_k(
    const bf16* __restrict__ xconv, const float* __restrict__ Gnt,
    const bf16* __restrict__ prev, const bf16* __restrict__ Cmb,
    const float* __restrict__ dtv, const float* __restrict__ acum,
    const float* __restrict__ Dp, bf16* __restrict__ Y)
{
  int bx = blockIdx.x;          // bc*NH + h
  int h = bx & 63, bc = bx >> 6;
  int b = bc >> 3, ci = bc & 7;
  long bl0 = (long)b * LQ + ci * CS;
  long abase = ((long)(b * NH + h) * NC + ci) * CS;
  int t = threadIdx.x;
  int wave = t >> 6, lane = t & 63;
  int quad = lane >> 4, r16 = lane & 15;
  int iw = wave * 64;

  __shared__ bf16 Xt[64][XTP];          // [p][k]: k<256 = X^T, k>=256 = prev^T
  __shared__ float a2s[CS], dts[CS], eas[CS];

  {
    float ac = acum[abase + t];
    a2s[t] = ac * LOG2E;
    dts[t] = dtv[abase + t];
    eas[t] = expf(ac);
  }
  {
    int col = t & 63, grp = t >> 6;
    for (int r = 0; r < 64; ++r) {
      int j = grp * 64 + r;
      Xt[col][j] = xconv[(bl0 + j) * INTER + h * HD + col];
    }
  }
  for (int r = 0; r < 32; ++r) {
    int idx = t + r * 256;
    int n = idx & 127, p = idx >> 7;
    Xt[p][256 + n] = prev[((long)bx * HD + p) * NS + n];
  }
  __syncthreads();

  f32x4 acc[4][4] = {};

  for (int kt = 0; kt < 12; ++kt) {
    int k0 = kt * 32;
    bool cpart = (k0 >= 256);
    if (!cpart && k0 > iw + 63) continue;   // whole k-tile above diagonal for this wave

    bf16x8 bfrag[4];
    #pragma unroll
    for (int nt = 0; nt < 4; ++nt)
      bfrag[nt] = *(const bf16x8*)&Xt[nt * 16 + r16][k0 + quad * 8];

    if (!cpart) {
      int j0 = k0 + quad * 8;
      float dt8[8], a28[8];
      *(float4*)&dt8[0] = *(const float4*)&dts[j0];
      *(float4*)&dt8[4] = *(const float4*)&dts[j0 + 4];
      *(float4*)&a28[0] = *(const float4*)&a2s[j0];
      *(float4*)&a28[4] = *(const float4*)&a2s[j0 + 4];
      #pragma unroll
      for (int it = 0; it < 4; ++it) {
        if (k0 > iw + it * 16 + 15) continue;   // zero tile
        int i = iw + it * 16 + r16;
        float a2i = a2s[i];
        const float* gp = &Gnt[((long)bc * CS + i) * CS + j0];
        float g[8];
        *(float4*)&g[0] = *(const float4*)gp;
        *(float4*)&g[4] = *(const float4*)(gp + 4);
        bf16x8 af;
        #pragma unroll
        for (int jj = 0; jj < 8; ++jj) {
          float v = g[jj] * dt8[jj] * exp2f(a2i - a28[jj]);
          v = (j0 + jj <= i) ? v : 0.f;
          af[jj] = (bf16)v;
        }
        #pragma unroll
        for (int nt = 0; nt < 4; ++nt)
          acc[it][nt] = __builtin_amdgcn_mfma_f32_16x16x32_bf16(af, bfrag[nt], acc[it][nt], 0, 0, 0);
      }
    } else {
      int n0 = k0 - 256 + quad * 8;
      #pragma unroll
      for (int it = 0; it < 4; ++it) {
        int i = iw + it * 16 + r16;
        float e = eas[i];
        bf16x8 cv = *(const bf16x8*)&Cmb[(bl0 + i) * NS + n0];
        bf16x8 af;
        #pragma unroll
        for (int jj = 0; jj < 8; ++jj)
          af[jj] = (bf16)(e * (float)cv[jj]);
        #pragma unroll
        for (int nt = 0; nt < 4; ++nt)
          acc[it][nt] = __builtin_amdgcn_mfma_f32_16x16x32_bf16(af, bfrag[nt], acc[it][nt], 0, 0, 0);
      }
    }
  }

  float Dh = Dp[h];
  #pragma unroll
  for (int it = 0; it < 4; ++it)
    #pragma unroll
    for (int nt = 0; nt < 4; ++nt) {
      int i0 = iw + it * 16 + quad * 4;
      int p  = nt * 16 + r16;
      bf16x4 xv = *(const bf16x4*)&Xt[p][i0];
      #pragma unroll
      for (int reg = 0; reg < 4; ++reg) {
        float v = acc[it][nt][reg] + Dh * (float)xv[reg];
        Y[(bl0 + i0 + reg) * INTER + h * HD + p] = (bf16)v;
      }
    }
}

// ---------------------------------------------------------------- gate*silu + RMS norm, IN PLACE (vectorized bf16x8)
__global__ __launch_bounds__(256) void norm_k(
    bf16* __restrict__ Y, const bf16* __restrict__ proj,
    const float* __restrict__ norm_w)
{
  long bl = blockIdx.x;
  int t = threadIdx.x;
  const bf16* yrow = Y + bl * INTER;
  const bf16* grow = proj + bl * PROJP;
  int c0 = t * 16;

  bf16x8 y0 = *(const bf16x8*)&yrow[c0];
  bf16x8 y1 = *(const bf16x8*)&yrow[c0 + 8];
  bf16x8 g0 = *(const bf16x8*)&grow[c0];
  bf16x8 g1 = *(const bf16x8*)&grow[c0 + 8];

  float yv[16];
  float ss = 0.f;
  #pragma unroll
  for (int j = 0; j < 8; ++j) {
    float g = (float)g0[j];
    float v = (float)y0[j] * (g / (1.f + expf(-g)));
    yv[j] = v; ss += v * v;
  }
  #pragma unroll
  for (int j = 0; j < 8; ++j) {
    float g = (float)g1[j];
    float v = (float)y1[j] * (g / (1.f + expf(-g)));
    yv[8 + j] = v; ss += v * v;
  }

  __shared__ float red[256];
  red[t] = ss;
  __syncthreads();
  for (int s = 128; s > 0; s >>= 1) {
    if (t < s) red[t] += red[t + s];
    __syncthreads();
  }
  float scale = rsqrtf(red[0] / (float)INTER + EPSF);

  float4 w0 = *(const float4*)&norm_w[c0];
  float4 w1 = *(const float4*)&norm_w[c0 + 4];
  float4 w2 = *(const float4*)&norm_w[c0 + 8];
  float4 w3 = *(const float4*)&norm_w[c0 + 12];
  float wv[16];
  *(float4*)&wv[0] = w0; *(float4*)&wv[4] = w1;
  *(float4*)&wv[8] = w2; *(float4*)&wv[12] = w3;

  bf16x8 o0, o1;
  #pragma unroll
  for (int j = 0; j < 8; ++j) o0[j] = (bf16)(yv[j] * scale * wv[j]);
  #pragma unroll
  for (int j = 0; j < 8; ++j) o1[j] = (bf16)(yv[8 + j] * scale * wv[8 + j]);
  *(bf16x8*)&Y[bl * INTER + c0]     = o0;
  *(bf16x8*)&Y[bl * INTER + c0 + 8] = o1;
}

// ---------------------------------------------------------------- launch
extern "C" void kernel_launch(void* const* d_in, const int* in_sizes, int n_in,
                              void* d_out, int out_size, void* d_ws, size_t ws_size,
                              hipStream_t stream)
{
  (void)in_sizes; (void)n_in; (void)out_size; (void)ws_size;
  const float* hidden  = (const float*)d_in[0];
  const float* W_in    = (const float*)d_in[1];
  const float* conv_w  = (const float*)d_in[2];
  const float* conv_b  = (const float*)d_in[3];
  const float* dt_bias = (const float*)d_in[4];
  const float* A_log   = (const float*)d_in[5];
  const float* Dp      = (const float*)d_in[6];
  const float* norm_w  = (const float*)d_in[7];
  const float* W_out   = (const float*)d_in[8];
  float* out = (float*)d_out;

  // ---- workspace layout with lifetime-based aliasing (peak ~124.7 MiB)
  char* ws    = (char*)d_ws;
  bf16* projb = (bf16*)(ws);                         // 70,254,592  [gemm1 .. norm]; then f32 split-K partials (67.1 MB)
  char* base2 = ws + 70254592;
  bf16*  hb    = (bf16*)(base2);                     // 16,777,216  [stage1 only]
  bf16*  winb  = (bf16*)(base2 + 16777216);          // 35,651,584  [stage1 only] (PROJW rows)
  bf16*  xconv = (bf16*)(base2);                     // 33,554,432  [conv .. ymix] = Y
  bf16*  st    = (bf16*)(base2 + 33554432);          // 16,777,216  [states .. ymix]
  float* Gnt   = (float*)(base2 + 50331648);         //  4,194,304
  bf16*  Bmb   = (bf16*)(base2 + 54525952);          //  1,048,576
  bf16*  Cmb   = (bf16*)(base2 + 55574528);          //  1,048,576
  float* dtv   = (float*)(base2 + 56623104);         //  1,048,576
  float* acum  = (float*)(base2 + 57671680);         //  1,048,576
  float* cdec  = (float*)(base2 + 58720256);         //      4,096
  bf16*  Bt    = (bf16*)(base2 + 58724352);          //  1,048,576 (B transposed per chunk)
  bf16*  Yb    = xconv;                              // alias (disjoint per-block tiles)
  bf16*  woutb = st;                                 // alias st (dead after ymix), exact 16 MiB

  // stage 1: casts + in-projection GEMM (256^2 pipelined, store-predicated to Nn=PROJP)
  cast4_k<<<dim3((unsigned)((MTOT * (long)DMODEL / 4 + 255) / 256)), 256, 0, stream>>>(
      hidden, hb, (long)MTOT * DMODEL / 4);
  cast_pad_win_k<<<dim3((unsigned)(((long)PROJW * (DMODEL / 4) + 255) / 256)), 256, 0, stream>>>(
      W_in, winb);
  gemm8<<<dim3((PROJW / 256) * (MTOT / 256)), 512, 0, stream>>>(
      hb, winb, projb, nullptr, MTOT, PROJP, PROJW / 256, DMODEL, 1, 0);

  // stage 2: conv + SSD
  conv_silu_k<<<dim3(CONVD / 256, MTOT), 256, 0, stream>>>(
      projb, conv_w, conv_b, xconv, Bmb, Cmb, Bt);
  dt_prep_k<<<dim3(BQ * NH * NC), CS, 0, stream>>>(
      projb, dt_bias, A_log, dtv, acum, cdec);
  gmat_k<<<dim3(4, BQ * NC), 256, 0, stream>>>(Cmb, Bmb, Gnt);
  states_k<<<dim3(BQ * NC * NH), 256, 0, stream>>>(xconv, Bt, dtv, acum, st);
  scan_k<<<dim3(BQ * NH * HD * NS / 256), 256, 0, stream>>>(st, cdec);
  ymix_k<<<dim3(BQ * NC * NH), 256, 0, stream>>>(
      xconv, Gnt, st, Cmb, dtv, acum, Dp, Yb);

  // stage 3: norm + out-projection GEMM (split-K=2 into f32 partials, then reduce)
  cast4_k<<<dim3((unsigned)((DMODEL * (long)INTER / 4 + 255) / 256)), 256, 0, stream>>>(
      W_out, woutb, (long)DMODEL * INTER / 4);
  norm_k<<<dim3(MTOT), 256, 0, stream>>>(Yb, projb, norm_w);
  gemm8<<<dim3((DMODEL / 256) * (MTOT / 256) * 2), 512, 0, stream>>>(
      Yb, woutb, nullptr, (float*)projb, MTOT, DMODEL, DMODEL / 256, INTER, 2, 1);
  addred_k<<<dim3((unsigned)((MTOT * (long)DMODEL / 4 + 255) / 256)), 256, 0, stream>>>(
      (const float*)projb, out, (long)MTOT * DMODEL / 4);
}